// Round 1
// baseline (886.133 us; speedup 1.0000x reference)
//
#include <hip/hip_runtime.h>
#include <hip/hip_bf16.h>

#define L_SEQ 2048
#define BSZ 2
#define DMODEL 1024
#define NHEAD 16
#define NROWS 4096  // L*BS

typedef __attribute__((ext_vector_type(8))) short bf16x8;
typedef __attribute__((ext_vector_type(4))) float f32x4;
typedef unsigned short u16;
typedef unsigned int u32;

__device__ __forceinline__ u16 f2bf(float x) {
  union { __hip_bfloat16 h; u16 u; } cv;
  cv.h = __float2bfloat16(x);
  return cv.u;
}

__device__ __forceinline__ void async16(void* lds, const void* g) {
  __builtin_amdgcn_global_load_lds(
      (const __attribute__((address_space(1))) void*)g,
      (__attribute__((address_space(3))) void*)lds, 16, 0, 0);
}

// ---------------- converts ----------------
__global__ __launch_bounds__(256) void cvt_kernel(const float* __restrict__ s,
                                                  u16* __restrict__ d, int n) {
  int i = (blockIdx.x * 256 + threadIdx.x) * 4;
  if (i >= n) return;
  float4 v = *(const float4*)(s + i);
  ushort4 o;
  o.x = f2bf(v.x); o.y = f2bf(v.y); o.z = f2bf(v.z); o.w = f2bf(v.w);
  *(ushort4*)(d + i) = o;
}

// V (4096x1024 f32) -> right half of combined (4096x2048 bf16)
__global__ __launch_bounds__(256) void cvtV_kernel(const float* __restrict__ s,
                                                   u16* __restrict__ comb) {
  int i = (blockIdx.x * 256 + threadIdx.x) * 4;
  if (i >= NROWS * DMODEL) return;
  int r = i >> 10, c = i & 1023;
  float4 v = *(const float4*)(s + i);
  ushort4 o;
  o.x = f2bf(v.x); o.y = f2bf(v.y); o.z = f2bf(v.z); o.w = f2bf(v.w);
  *(ushort4*)(comb + (size_t)r * 2048 + 1024 + c) = o;
}

// ---------------- GEMM: C(MxN) = A(MxK) @ B(NxK)^T, bf16 in, fp32 acc -------
__global__ __launch_bounds__(256) void gemm_bt(
    const u16* __restrict__ A, const u16* __restrict__ B,
    const float* __restrict__ bias, float scale,
    u16* __restrict__ Cb, float* __restrict__ Cf, float* __restrict__ ksq_out,
    int M, int N, int K) {
  __shared__ u16 As[128 * 64];
  __shared__ u16 Bs[128 * 64];
  const int tid = threadIdx.x;
  const int w = tid >> 6, lane = tid & 63;
  const int quad = lane >> 4, m16 = lane & 15;
  const int wr = w >> 1, wc = w & 1;
  const int m0 = blockIdx.y * 128, n0 = blockIdx.x * 128;
  f32x4 acc[4][4] = {};

  for (int kt = 0; kt < K; kt += 64) {
    __syncthreads();
#pragma unroll
    for (int j = 0; j < 4; ++j) {
      int chunk = (w * 4 + j) * 64 + lane;  // 0..1023, 16B each
      int row = chunk >> 3, kc = chunk & 7;
      async16(As + (size_t)(w * 4 + j) * 512,
              A + (size_t)(m0 + row) * K + kt + kc * 8);
      async16(Bs + (size_t)(w * 4 + j) * 512,
              B + (size_t)(n0 + row) * K + kt + kc * 8);
    }
    __syncthreads();
#pragma unroll
    for (int kk = 0; kk < 2; ++kk) {
      bf16x8 af[4], bfr[4];
#pragma unroll
      for (int i = 0; i < 4; ++i)
        af[i] = *(const bf16x8*)(As + (wr * 64 + i * 16 + m16) * 64 + kk * 32 + quad * 8);
#pragma unroll
      for (int j = 0; j < 4; ++j)
        bfr[j] = *(const bf16x8*)(Bs + (wc * 64 + j * 16 + m16) * 64 + kk * 32 + quad * 8);
#pragma unroll
      for (int i = 0; i < 4; ++i)
#pragma unroll
        for (int j = 0; j < 4; ++j)
          acc[i][j] = __builtin_amdgcn_mfma_f32_16x16x32_bf16(af[i], bfr[j], acc[i][j], 0, 0, 0);
    }
  }

#pragma unroll
  for (int i = 0; i < 4; ++i) {
    int R0 = m0 + wr * 64 + i * 16 + quad * 4;
    float ksq_part[4] = {0.f, 0.f, 0.f, 0.f};
#pragma unroll
    for (int j = 0; j < 4; ++j) {
      int C = n0 + wc * 64 + j * 16 + m16;
      float bv = bias ? bias[C] : 0.0f;
#pragma unroll
      for (int r = 0; r < 4; ++r) {
        float v = (acc[i][j][r] + bv) * scale;
        size_t idx = (size_t)(R0 + r) * N + C;
        if (Cb) Cb[idx] = f2bf(v);
        if (Cf) Cf[idx] = v;
        if (ksq_out) ksq_part[r] += v * v;
      }
    }
    if (ksq_out) {
#pragma unroll
      for (int r = 0; r < 4; ++r) {
        float t = ksq_part[r];
        t += __shfl_xor(t, 1); t += __shfl_xor(t, 2);
        t += __shfl_xor(t, 4); t += __shfl_xor(t, 8);
        if (m16 == 0) {
          int R = R0 + r;
          int bb = R & 1, l = R >> 1;
          int h = (n0 + wc * 64) >> 6;
          ksq_out[(size_t)(bb * NHEAD + h) * L_SEQ + l] = t;
        }
      }
    }
  }
}

// ---------------- attention ----------------
// block: 64 q-rows of one (b,h). scores = qp.kp - ksq (scales pre-folded).
__global__ __launch_bounds__(256) void attn_kernel(
    const u16* __restrict__ qp, const u16* __restrict__ kp,
    const float* __restrict__ ksqg, const u16* __restrict__ comb_v,
    u16* __restrict__ comb_o, float* __restrict__ attn_out) {
  __shared__ u16 Qs[64 * 64];
  __shared__ u16 Ks[64 * 64];
  __shared__ u16 Vst[64 * 64];  // [d][key]
  __shared__ u16 Ps[4 * 16 * 64];
  __shared__ float ksq_s[64];
  const int tid = threadIdx.x;
  const int w = tid >> 6, lane = tid & 63;
  const int quad = lane >> 4, m16 = lane & 15;
  const int qt = blockIdx.x, bh = blockIdx.y;
  const int b = bh >> 4, h = bh & 15;
  const int q0 = qt * 64;

#pragma unroll
  for (int j = 0; j < 2; ++j) {
    int chunk = (w * 2 + j) * 64 + lane;  // 0..511
    int row = chunk >> 3, kc = chunk & 7;
    async16(Qs + (size_t)(w * 2 + j) * 512,
            qp + (size_t)((q0 + row) * 2 + b) * 1024 + h * 64 + kc * 8);
  }
  __syncthreads();
  bf16x8 aq0 = *(const bf16x8*)(Qs + (w * 16 + m16) * 64 + quad * 8);
  bf16x8 aq1 = *(const bf16x8*)(Qs + (w * 16 + m16) * 64 + 32 + quad * 8);

  // pass A: row sums of exp(s). (s <= ||q||^2 ~ 2.5, no max needed)
  float lsum[4] = {0.f, 0.f, 0.f, 0.f};
  for (int kt = 0; kt < 32; ++kt) {
    __syncthreads();
#pragma unroll
    for (int j = 0; j < 2; ++j) {
      int chunk = (w * 2 + j) * 64 + lane;
      int row = chunk >> 3, kc = chunk & 7;
      async16(Ks + (size_t)(w * 2 + j) * 512,
              kp + (size_t)((kt * 64 + row) * 2 + b) * 1024 + h * 64 + kc * 8);
    }
    if (tid < 64) ksq_s[tid] = ksqg[(size_t)bh * L_SEQ + kt * 64 + tid];
    __syncthreads();
#pragma unroll
    for (int j = 0; j < 4; ++j) {
      bf16x8 bk0 = *(const bf16x8*)(Ks + (j * 16 + m16) * 64 + quad * 8);
      bf16x8 bk1 = *(const bf16x8*)(Ks + (j * 16 + m16) * 64 + 32 + quad * 8);
      f32x4 s4 = {0.f, 0.f, 0.f, 0.f};
      s4 = __builtin_amdgcn_mfma_f32_16x16x32_bf16(aq0, bk0, s4, 0, 0, 0);
      s4 = __builtin_amdgcn_mfma_f32_16x16x32_bf16(aq1, bk1, s4, 0, 0, 0);
      float kq = ksq_s[j * 16 + m16];
#pragma unroll
      for (int r = 0; r < 4; ++r) lsum[r] += __expf(s4[r] - kq);
    }
  }
#pragma unroll
  for (int r = 0; r < 4; ++r) {
    float t = lsum[r];
    t += __shfl_xor(t, 1); t += __shfl_xor(t, 2);
    t += __shfl_xor(t, 4); t += __shfl_xor(t, 8);
    lsum[r] = 1.0f / t;
  }

  // pass B: recompute S, write attn, P@V
  f32x4 o[4] = {};
  for (int kt = 0; kt < 32; ++kt) {
    __syncthreads();
#pragma unroll
    for (int j = 0; j < 2; ++j) {
      int chunk = (w * 2 + j) * 64 + lane;
      int row = chunk >> 3, kc = chunk & 7;
      async16(Ks + (size_t)(w * 2 + j) * 512,
              kp + (size_t)((kt * 64 + row) * 2 + b) * 1024 + h * 64 + kc * 8);
    }
#pragma unroll
    for (int it = 0; it < 2; ++it) {  // V transpose: [key][d] -> [d][key]
      int chunk = it * 256 + tid;
      int key = chunk >> 3, dc = chunk & 7;
      const u16* gp = comb_v + (size_t)((kt * 64 + key) * 2 + b) * 2048 + 1024 + h * 64 + dc * 8;
      uint4 u = *(const uint4*)gp;
      u32 parts[4] = {u.x, u.y, u.z, u.w};
#pragma unroll
      for (int q2 = 0; q2 < 4; ++q2) {
        Vst[(dc * 8 + q2 * 2 + 0) * 64 + key] = (u16)(parts[q2] & 0xffffu);
        Vst[(dc * 8 + q2 * 2 + 1) * 64 + key] = (u16)(parts[q2] >> 16);
      }
    }
    if (tid < 64) ksq_s[tid] = ksqg[(size_t)bh * L_SEQ + kt * 64 + tid];
    __syncthreads();
#pragma unroll
    for (int j = 0; j < 4; ++j) {
      bf16x8 bk0 = *(const bf16x8*)(Ks + (j * 16 + m16) * 64 + quad * 8);
      bf16x8 bk1 = *(const bf16x8*)(Ks + (j * 16 + m16) * 64 + 32 + quad * 8);
      f32x4 s4 = {0.f, 0.f, 0.f, 0.f};
      s4 = __builtin_amdgcn_mfma_f32_16x16x32_bf16(aq0, bk0, s4, 0, 0, 0);
      s4 = __builtin_amdgcn_mfma_f32_16x16x32_bf16(aq1, bk1, s4, 0, 0, 0);
      float kq = ksq_s[j * 16 + m16];
      size_t abase = ((size_t)bh * L_SEQ + q0 + w * 16 + quad * 4) * L_SEQ + kt * 64 + j * 16 + m16;
#pragma unroll
      for (int r = 0; r < 4; ++r) {
        float p = __expf(s4[r] - kq) * lsum[r];
        attn_out[abase + (size_t)r * L_SEQ] = p;
        Ps[w * 1024 + (quad * 4 + r) * 64 + j * 16 + m16] = f2bf(p);
      }
    }
    __syncthreads();
#pragma unroll
    for (int kk = 0; kk < 2; ++kk) {
      bf16x8 pa = *(const bf16x8*)(Ps + w * 1024 + m16 * 64 + kk * 32 + quad * 8);
#pragma unroll
      for (int j2 = 0; j2 < 4; ++j2) {
        bf16x8 bv = *(const bf16x8*)(Vst + (j2 * 16 + m16) * 64 + kk * 32 + quad * 8);
        o[j2] = __builtin_amdgcn_mfma_f32_16x16x32_bf16(pa, bv, o[j2], 0, 0, 0);
      }
    }
  }
#pragma unroll
  for (int j2 = 0; j2 < 4; ++j2) {
#pragma unroll
    for (int r = 0; r < 4; ++r) {
      int qrow = q0 + w * 16 + quad * 4 + r;
      comb_o[(size_t)(qrow * 2 + b) * 2048 + h * 64 + j2 * 16 + m16] = f2bf(o[j2][r]);
    }
  }
}

extern "C" void kernel_launch(void* const* d_in, const int* in_sizes, int n_in,
                              void* d_out, int out_size, void* d_ws, size_t ws_size,
                              hipStream_t stream) {
  const float* Q  = (const float*)d_in[0];
  const float* K  = (const float*)d_in[1];
  const float* V  = (const float*)d_in[2];
  const float* WQ = (const float*)d_in[3];
  const float* bQ = (const float*)d_in[4];
  const float* WK = (const float*)d_in[5];
  const float* bK = (const float*)d_in[6];
  const float* Wp = (const float*)d_in[7];
  const float* bp = (const float*)d_in[8];
  float* proj_out = (float*)d_out;
  float* attn_out = proj_out + (size_t)NROWS * DMODEL;

  char* ws = (char*)d_ws;
  const size_t MB = 1u << 20;
  u16* Qb   = (u16*)(ws + 0 * MB);    // 8 MB
  u16* Kb   = (u16*)(ws + 8 * MB);    // 8 MB
  u16* WQb  = (u16*)(ws + 16 * MB);   // 2 MB
  u16* WKb  = (u16*)(ws + 18 * MB);   // 2 MB
  u16* Wpb  = (u16*)(ws + 20 * MB);   // 4 MB
  u16* qpb  = (u16*)(ws + 24 * MB);   // 8 MB (pre-scaled by 0.25)
  u16* kpb  = (u16*)(ws + 32 * MB);   // 8 MB
  u16* comb = (u16*)(ws + 40 * MB);   // 16 MB (4096x2048: [attn_out | V])
  float* ksqb = (float*)(ws + 56 * MB);  // 256 KB

  cvt_kernel<<<4096, 256, 0, stream>>>(Q, Qb, NROWS * DMODEL);
  cvt_kernel<<<4096, 256, 0, stream>>>(K, Kb, NROWS * DMODEL);
  cvt_kernel<<<1024, 256, 0, stream>>>(WQ, WQb, DMODEL * DMODEL);
  cvt_kernel<<<1024, 256, 0, stream>>>(WK, WKb, DMODEL * DMODEL);
  cvt_kernel<<<2048, 256, 0, stream>>>(Wp, Wpb, DMODEL * 2 * DMODEL);
  cvtV_kernel<<<4096, 256, 0, stream>>>(V, comb);

  // qp = 0.25*(Q @ WQ^T + bQ)   [score = qp.kp - ksq]
  gemm_bt<<<dim3(8, 32), 256, 0, stream>>>(Qb, WQb, bQ, 0.25f, qpb, nullptr, nullptr,
                                           NROWS, DMODEL, DMODEL);
  // kp = K @ WK^T + bK, plus fp32 ksq per (b,h,l)
  gemm_bt<<<dim3(8, 32), 256, 0, stream>>>(Kb, WKb, bK, 1.0f, kpb, nullptr, ksqb,
                                           NROWS, DMODEL, DMODEL);
  attn_kernel<<<dim3(32, 32), 256, 0, stream>>>(qpb, kpb, ksqb, comb, comb, attn_out);
  // proj = [out|V] @ Wp^T + bp
  gemm_bt<<<dim3(8, 32), 256, 0, stream>>>(comb, Wpb, bp, 1.0f, nullptr, proj_out, nullptr,
                                           NROWS, DMODEL, 2 * DMODEL);
}